// Round 2
// baseline (875.456 us; speedup 1.0000x reference)
//
#include <hip/hip_runtime.h>
#include <hip/hip_bf16.h>
#include <stdint.h>

#define NE 8
#define NTOK 8192        // B*T
#define HD 1024
#define FD 4096
#define NSLOT (NTOK * 2)
#define NSEG 16
#define SEGLEN (NSLOT / NSEG)

typedef __attribute__((ext_vector_type(4))) float floatx4;
typedef __attribute__((ext_vector_type(8))) __bf16 bf16x8;
typedef __attribute__((ext_vector_type(8))) unsigned short ushortx8;

__device__ __forceinline__ unsigned short f2bf(float f) {
    union { float f; unsigned u; } v; v.f = f;
    unsigned r = v.u + 0x7FFFu + ((v.u >> 16) & 1u);   // RNE
    return (unsigned short)(r >> 16);
}

__device__ __forceinline__ void gload_lds16(const unsigned short* g, unsigned short* l) {
    __builtin_amdgcn_global_load_lds(
        (const __attribute__((address_space(1))) void*)g,
        (__attribute__((address_space(3))) void*)l,
        16, 0, 0);
}

// ------------- transpose + cast: w[e][r][c] (fp32) -> wt[e][c][r] (bf16) -------------
__global__ void transpose_cast_kernel(const float* __restrict__ w, unsigned short* __restrict__ wt,
                                      int rows, int cols) {
    __shared__ unsigned short tile[64][66];
    int e = blockIdx.z;
    int r0 = blockIdx.y * 64;
    int c0 = blockIdx.x * 64;
    const float* ws = w + (size_t)e * rows * cols;
    unsigned short* wd = wt + (size_t)e * rows * cols;
    int tid = threadIdx.x;   // 256
#pragma unroll
    for (int j = 0; j < 4; j++) {
        int idx = j * 256 + tid;
        int r = idx >> 4;
        int c4 = (idx & 15) * 4;
        float4 v = *(const float4*)(ws + (size_t)(r0 + r) * cols + c0 + c4);
        ushort2 lo, hi;
        lo.x = f2bf(v.x); lo.y = f2bf(v.y);
        hi.x = f2bf(v.z); hi.y = f2bf(v.w);
        *(ushort2*)&tile[r][c4]     = lo;
        *(ushort2*)&tile[r][c4 + 2] = hi;
    }
    __syncthreads();
#pragma unroll
    for (int j = 0; j < 2; j++) {
        int idx = j * 256 + tid;
        int c = idx >> 3;
        int r8 = (idx & 7) * 8;
        ushortx8 o;
#pragma unroll
        for (int k = 0; k < 8; k++) o[k] = tile[r8 + k][c];
        *(ushortx8*)(wd + (size_t)(c0 + c) * rows + r0 + r8) = o;
    }
}

// -------- router phase A: logits, top-2 softmax, eid/wts per slot, x->bf16 cast --------
__global__ void router_kernel(const float* __restrict__ x, const float* __restrict__ gw,
                              float* __restrict__ logits, int* __restrict__ eid,
                              float* __restrict__ wts, unsigned short* __restrict__ xb) {
    int lane = threadIdx.x & 63;
    int t = blockIdx.x * 4 + (threadIdx.x >> 6);   // one wave per token
    const float* xr = x + (size_t)t * HD;
    unsigned short* xbr = xb + (size_t)t * HD;
    float a0=0,a1=0,a2=0,a3=0,a4=0,a5=0,a6=0,a7=0;
    for (int c = lane; c < HD; c += 64) {
        float xv = xr[c];
        xbr[c] = f2bf(xv);
        const float4* g = (const float4*)(gw + (size_t)c * NE);
        float4 g0 = g[0], g1 = g[1];
        a0 += xv * g0.x; a1 += xv * g0.y; a2 += xv * g0.z; a3 += xv * g0.w;
        a4 += xv * g1.x; a5 += xv * g1.y; a6 += xv * g1.z; a7 += xv * g1.w;
    }
#pragma unroll
    for (int off = 32; off > 0; off >>= 1) {
        a0 += __shfl_xor(a0, off); a1 += __shfl_xor(a1, off);
        a2 += __shfl_xor(a2, off); a3 += __shfl_xor(a3, off);
        a4 += __shfl_xor(a4, off); a5 += __shfl_xor(a5, off);
        a6 += __shfl_xor(a6, off); a7 += __shfl_xor(a7, off);
    }
    if (lane == 0) {
        float l[8] = {a0,a1,a2,a3,a4,a5,a6,a7};
        float4 s0 = make_float4(a0,a1,a2,a3);
        float4 s1 = make_float4(a4,a5,a6,a7);
        ((float4*)(logits + (size_t)t * NE))[0] = s0;
        ((float4*)(logits + (size_t)t * NE))[1] = s1;
        int e0 = 0; float v0 = l[0];
#pragma unroll
        for (int e = 1; e < 8; e++) if (l[e] > v0) { v0 = l[e]; e0 = e; }
        int e1 = -1; float v1 = -3.4e38f;
#pragma unroll
        for (int e = 0; e < 8; e++) if (e != e0 && l[e] > v1) { v1 = l[e]; e1 = e; }
        float ex = __expf(v1 - v0);
        float dn = 1.f + ex;
        wts[2*t]   = 1.f / dn;
        wts[2*t+1] = ex / dn;
        eid[2*t]   = e0;
        eid[2*t+1] = e1;
    }
}

// -------- router phase B: hierarchical perm build --------
__global__ void count_seg_kernel(const int* __restrict__ eid, int* __restrict__ segcnt) {
    int e = blockIdx.x >> 4;
    int seg = blockIdx.x & 15;
    int lane = threadIdx.x;       // 64
    int base = seg * SEGLEN;
    int cnt = 0;
    for (int i0 = 0; i0 < SEGLEN; i0 += 64) {
        bool mt = (eid[base + i0 + lane] == e);
        cnt += __popcll(__ballot(mt));
    }
    if (lane == 0) segcnt[blockIdx.x] = cnt;
}

__global__ void fill_perm_kernel(const int* __restrict__ eid, const int* __restrict__ segcnt,
                                 int* __restrict__ perm, int* __restrict__ counts) {
    int e = blockIdx.x >> 4;
    int seg = blockIdx.x & 15;
    int lane = threadIdx.x;       // 64
    int base = 0;
#pragma unroll
    for (int s2 = 0; s2 < NSEG; s2++)
        if (s2 < seg) base += segcnt[(e << 4) + s2];
    int* permE = perm + e * NTOK;
    int g0 = seg * SEGLEN;
    for (int i0 = 0; i0 < SEGLEN; i0 += 64) {
        int s = g0 + i0 + lane;
        bool mt = (eid[s] == e);
        unsigned long long mask = __ballot(mt);
        int pre = __popcll(mask & ((1ULL << lane) - 1ULL));
        if (mt) permE[base + pre] = s;
        base += __popcll(mask);
    }
    if (lane == 0 && seg == NSEG - 1) counts[e] = base;
}

// ---------------- gathered GEMM: 256x256x64 tile, 512 threads, counted-vmcnt dbuf ----------------
// C[M x NTOT] = gather(A)[M x KTOT] * Bt[e]^T, Bt stored [NTOT x KTOT] (B^T).
// G1: A row = xb[slot>>1], epilogue relu->bf16 into h[slot].
// !G1: A row = h[slot], epilogue atomicAdd(out[slot>>1], w[slot]*acc).
// 8 waves in 2x4 (M x N): per-wave 128x64 output = acc[8][4] fragments.
// Per K-iter: 512 MFMA x 4.85 cyc ~ 2480 cyc/CU >> 900 cyc HBM latency -> prefetch hidden.
template<int KTOT, int NTOT, bool G1>
__global__ __launch_bounds__(512, 2)
void moe_gemm(const unsigned short* __restrict__ A,
              const unsigned short* __restrict__ Bt,
              unsigned short* __restrict__ Hout,
              float* __restrict__ Out,
              const int* __restrict__ counts,
              const int* __restrict__ perm,
              const float* __restrict__ wts) {
    // bid%8 == XCD id; XCD k owns expert k. Within an expert, 4x4 (mtile,ntile)
    // supertiles: A-slab + B-slab ~4 MiB -> fits the 4 MiB per-XCD L2.
    constexpr int GX = NTOT / 256;    // n-tiles: 16 (G1) or 4 (!G1)
    constexpr int SN = GX / 4;        // n-supergroups: 4 or 1
    int bid = blockIdx.y * GX + blockIdx.x;
    int e = bid & 7;
    int i = bid >> 3;                 // [0, GX*32)
    int st = i >> 4, pos = i & 15;
    int mg = st / SN, ng = st % SN;   // mg-major: consecutive supertiles reuse the A slab
    int mtile = mg * 4 + (pos >> 2);
    int n0 = (ng * 4 + (pos & 3)) * 256;

    int cnt = counts[e];
    if (mtile * 256 >= cnt) return;

    __shared__ unsigned short lds[2 * 32768];   // 128 KiB: [buf][A 16K | B 16K] elems

    int tid = threadIdx.x;            // 512
    int lane = tid & 63;
    int wv = tid >> 6;                // 0..7
    const int* permE = perm + e * NTOK + mtile * 256;

    // staging: thread covers rows r_it = it*64 + (tid>>3), chunk tid&7 (16B chunks of 128B rows)
    const unsigned short* aRow[4];
    const unsigned short* bRow[4];
#pragma unroll
    for (int it = 0; it < 4; it++) {
        int r = it * 64 + (tid >> 3);
        int s = (mtile * 256 + r < cnt) ? permE[r] : permE[0];   // clamp to a valid row
        size_t arow = G1 ? (size_t)(s >> 1) : (size_t)s;
        aRow[it] = A + arow * KTOT;
        bRow[it] = Bt + ((size_t)e * NTOT + n0 + r) * KTOT;
    }
    // XOR swizzle: logical k-chunk j of row r lives at physical chunk j^(r&7)
    // (pre-swizzled global source, linear LDS dest — global_load_lds requirement).
    int koff = ((tid & 7) ^ ((tid >> 3) & 7)) * 8;   // elements
    int wbase = (tid & 448) * 8;                     // wave-uniform LDS base: wv*512 elems

    floatx4 acc[8][4];
    floatx4 zero = {0.f, 0.f, 0.f, 0.f};
#pragma unroll
    for (int a = 0; a < 8; a++)
#pragma unroll
        for (int b = 0; b < 4; b++) acc[a][b] = zero;

    int m = lane & 15, quad = lane >> 4;
    int wr = wv >> 2, wc = wv & 3;
    int rA = wr * 128 + m;           // + mi*16, mi 0..7
    int rB = wc * 64 + m;            // + ni*16, ni 0..3
    int xs = m & 7;                  // fragment-read swizzle (row&7 == m&7)

    constexpr int NK = KTOT / 64;

    auto stage = [&](int buf, int k0) {
        unsigned short* la = &lds[buf * 32768];
        unsigned short* lb = la + 16384;
#pragma unroll
        for (int it = 0; it < 4; it++)
            gload_lds16(aRow[it] + k0 + koff, la + it * 4096 + wbase);
#pragma unroll
        for (int it = 0; it < 4; it++)
            gload_lds16(bRow[it] + k0 + koff, lb + it * 4096 + wbase);
    };

    stage(0, 0);                         // prologue: tile 0 in flight (8 loads/thread)
    int cur = 0;
#pragma unroll 2
    for (int kt = 0; kt < NK; kt++) {
        if (kt + 1 < NK) {
            stage(cur ^ 1, (kt + 1) * 64);                    // prefetch next tile (8 loads)
            asm volatile("s_waitcnt vmcnt(8)" ::: "memory");  // wait ONLY tile kt's 8
        } else {
            asm volatile("s_waitcnt vmcnt(0)" ::: "memory");
        }
        __builtin_amdgcn_sched_barrier(0);
        __builtin_amdgcn_s_barrier();                         // raw: no vmcnt(0) drain
        __builtin_amdgcn_sched_barrier(0);

        const unsigned short* la = &lds[cur * 32768];
        const unsigned short* lb = la + 16384;
#pragma unroll
        for (int kk = 0; kk < 2; kk++) {
            bf16x8 af[8], bfr[4];
#pragma unroll
            for (int mi = 0; mi < 8; mi++)
                af[mi] = *(const bf16x8*)(la + (((rA + mi * 16) * 8 + ((kk * 4 + quad) ^ xs)) * 8));
#pragma unroll
            for (int ni = 0; ni < 4; ni++)
                bfr[ni] = *(const bf16x8*)(lb + (((rB + ni * 16) * 8 + ((kk * 4 + quad) ^ xs)) * 8));
            __builtin_amdgcn_s_setprio(1);
#pragma unroll
            for (int mi = 0; mi < 8; mi++)
#pragma unroll
                for (int ni = 0; ni < 4; ni++)
                    acc[mi][ni] = __builtin_amdgcn_mfma_f32_16x16x32_bf16(af[mi], bfr[ni], acc[mi][ni], 0, 0, 0);
            __builtin_amdgcn_s_setprio(0);
        }
        // all my LDS reads done before anyone overwrites this buffer next iteration
        asm volatile("s_waitcnt lgkmcnt(0)" ::: "memory");
        __builtin_amdgcn_sched_barrier(0);
        __builtin_amdgcn_s_barrier();
        __builtin_amdgcn_sched_barrier(0);
        cur ^= 1;
    }

    // epilogue: C/D layout col = lane&15 (+ni*16), row = quad*4 + reg (+mi*16)
    int colb = wc * 64 + m;
    int rb = wr * 128 + quad * 4;
#pragma unroll
    for (int mi = 0; mi < 8; mi++) {
#pragma unroll
        for (int reg = 0; reg < 4; reg++) {
            int rl = rb + mi * 16 + reg;
            if (mtile * 256 + rl >= cnt) continue;
            int s = permE[rl];             // 1 KiB segment, L2-hot
            if (G1) {
                unsigned short* hr = Hout + (size_t)s * NTOT + n0 + colb;
#pragma unroll
                for (int ni = 0; ni < 4; ni++) {
                    float v = acc[mi][ni][reg];
                    hr[ni * 16] = f2bf(v > 0.f ? v : 0.f);
                }
            } else {
                float w = wts[s];
                float* orow = Out + (size_t)(s >> 1) * NTOT + n0 + colb;
#pragma unroll
                for (int ni = 0; ni < 4; ni++)
                    atomicAdd(&orow[ni * 16], w * acc[mi][ni][reg]);
            }
        }
    }
}

extern "C" void kernel_launch(void* const* d_in, const int* in_sizes, int n_in,
                              void* d_out, int out_size, void* d_ws, size_t ws_size,
                              hipStream_t stream) {
    (void)in_sizes; (void)n_in; (void)out_size;
    const float* x  = (const float*)d_in[0];
    const float* gw = (const float*)d_in[1];
    const float* w1 = (const float*)d_in[2];
    const float* w2 = (const float*)d_in[3];
    float* out = (float*)d_out;
    float* logits = out + (size_t)NTOK * HD;

    char* ws = (char*)d_ws;
    int*   counts = (int*)ws;                                   // 256 B
    int*   perm   = (int*)(ws + 256);                           // 8*8192*4 = 256 KiB
    float* wts    = (float*)(ws + 256 + 262144);                // 64 KiB
    int*   eid    = (int*)(ws + 256 + 262144 + 65536);          // 64 KiB
    int*   segcnt = (int*)(ws + 393472);                        // 512 B (in the pre-xb gap)
    unsigned short* xb    = (unsigned short*)(ws + 458752);                // 16 MiB
    unsigned short* wtbuf = xb + (size_t)NTOK * HD;                        // 64 MiB (w1t, then w2t)
    unsigned short* h     = wtbuf + (size_t)NE * HD * FD;                  // 128 MiB
    size_t needed = 458752 + (size_t)NTOK*HD*2 + (size_t)NE*HD*FD*2 + (size_t)NSLOT*FD*2;
    if (ws_size < needed) return;   // workspace too small — cannot run

    hipMemsetAsync(out, 0, (size_t)NTOK * HD * sizeof(float), stream);

    // w1: [E][H][F] -> w1t [E][F][H]  (rows=H, cols=F)
    transpose_cast_kernel<<<dim3(FD / 64, HD / 64, NE), 256, 0, stream>>>(w1, wtbuf, HD, FD);
    router_kernel<<<NTOK / 4, 256, 0, stream>>>(x, gw, logits, eid, wts, xb);
    count_seg_kernel<<<NE * NSEG, 64, 0, stream>>>(eid, segcnt);
    fill_perm_kernel<<<NE * NSEG, 64, 0, stream>>>(eid, segcnt, perm, counts);
    // h[s] = relu(xb[token] @ w1[e]) : K=1024, N=4096
    moe_gemm<HD, FD, true><<<dim3(FD / 256, NE * 32), 512, 0, stream>>>(
        xb, wtbuf, h, nullptr, counts, perm, wts);
    // w2: [E][F][H] -> w2t [E][H][F] (reuse wtbuf; stream order serializes after gemm1)
    transpose_cast_kernel<<<dim3(HD / 64, FD / 64, NE), 256, 0, stream>>>(w2, wtbuf, FD, HD);
    // out[t] += w[s] * (h[s] @ w2[e]) : K=4096, N=1024
    moe_gemm<FD, HD, false><<<dim3(HD / 256, NE * 32), 512, 0, stream>>>(
        h, wtbuf, nullptr, out, counts, perm, wts);
}

// Round 3
// 745.086 us; speedup vs baseline: 1.1750x; 1.1750x over previous
//
#include <hip/hip_runtime.h>
#include <hip/hip_bf16.h>
#include <stdint.h>

#define NE 8
#define NTOK 8192        // B*T
#define HD 1024
#define FD 4096
#define NSLOT (NTOK * 2)
#define NSEG 16
#define SEGLEN (NSLOT / NSEG)

typedef __attribute__((ext_vector_type(4))) float floatx4;
typedef __attribute__((ext_vector_type(8))) __bf16 bf16x8;
typedef __attribute__((ext_vector_type(8))) unsigned short ushortx8;

__device__ __forceinline__ unsigned short f2bf(float f) {
    union { float f; unsigned u; } v; v.f = f;
    unsigned r = v.u + 0x7FFFu + ((v.u >> 16) & 1u);   // RNE
    return (unsigned short)(r >> 16);
}

__device__ __forceinline__ void gload_lds16(const unsigned short* g, unsigned short* l) {
    __builtin_amdgcn_global_load_lds(
        (const __attribute__((address_space(1))) void*)g,
        (__attribute__((address_space(3))) void*)l,
        16, 0, 0);
}

#define WAITVM(n) asm volatile("s_waitcnt vmcnt(" #n ")" ::: "memory")

// ------------- transpose + cast: w[e][r][c] (fp32) -> wt[e][c][r] (bf16) -------------
__global__ void transpose_cast_kernel(const float* __restrict__ w, unsigned short* __restrict__ wt,
                                      int rows, int cols) {
    __shared__ unsigned short tile[64][66];
    int e = blockIdx.z;
    int r0 = blockIdx.y * 64;
    int c0 = blockIdx.x * 64;
    const float* ws = w + (size_t)e * rows * cols;
    unsigned short* wd = wt + (size_t)e * rows * cols;
    int tid = threadIdx.x;   // 256
#pragma unroll
    for (int j = 0; j < 4; j++) {
        int idx = j * 256 + tid;
        int r = idx >> 4;
        int c4 = (idx & 15) * 4;
        float4 v = *(const float4*)(ws + (size_t)(r0 + r) * cols + c0 + c4);
        ushort2 lo, hi;
        lo.x = f2bf(v.x); lo.y = f2bf(v.y);
        hi.x = f2bf(v.z); hi.y = f2bf(v.w);
        *(ushort2*)&tile[r][c4]     = lo;
        *(ushort2*)&tile[r][c4 + 2] = hi;
    }
    __syncthreads();
#pragma unroll
    for (int j = 0; j < 2; j++) {
        int idx = j * 256 + tid;
        int c = idx >> 3;
        int r8 = (idx & 7) * 8;
        ushortx8 o;
#pragma unroll
        for (int k = 0; k < 8; k++) o[k] = tile[r8 + k][c];
        *(ushortx8*)(wd + (size_t)(c0 + c) * rows + r0 + r8) = o;
    }
}

// -------- router phase A: logits, top-2 softmax, eid/wts per slot, x->bf16 cast --------
__global__ void router_kernel(const float* __restrict__ x, const float* __restrict__ gw,
                              float* __restrict__ logits, int* __restrict__ eid,
                              float* __restrict__ wts, unsigned short* __restrict__ xb) {
    int lane = threadIdx.x & 63;
    int t = blockIdx.x * 4 + (threadIdx.x >> 6);   // one wave per token
    const float* xr = x + (size_t)t * HD;
    unsigned short* xbr = xb + (size_t)t * HD;
    float a0=0,a1=0,a2=0,a3=0,a4=0,a5=0,a6=0,a7=0;
    for (int c = lane; c < HD; c += 64) {
        float xv = xr[c];
        xbr[c] = f2bf(xv);
        const float4* g = (const float4*)(gw + (size_t)c * NE);
        float4 g0 = g[0], g1 = g[1];
        a0 += xv * g0.x; a1 += xv * g0.y; a2 += xv * g0.z; a3 += xv * g0.w;
        a4 += xv * g1.x; a5 += xv * g1.y; a6 += xv * g1.z; a7 += xv * g1.w;
    }
#pragma unroll
    for (int off = 32; off > 0; off >>= 1) {
        a0 += __shfl_xor(a0, off); a1 += __shfl_xor(a1, off);
        a2 += __shfl_xor(a2, off); a3 += __shfl_xor(a3, off);
        a4 += __shfl_xor(a4, off); a5 += __shfl_xor(a5, off);
        a6 += __shfl_xor(a6, off); a7 += __shfl_xor(a7, off);
    }
    if (lane == 0) {
        float l[8] = {a0,a1,a2,a3,a4,a5,a6,a7};
        float4 s0 = make_float4(a0,a1,a2,a3);
        float4 s1 = make_float4(a4,a5,a6,a7);
        ((float4*)(logits + (size_t)t * NE))[0] = s0;
        ((float4*)(logits + (size_t)t * NE))[1] = s1;
        int e0 = 0; float v0 = l[0];
#pragma unroll
        for (int e = 1; e < 8; e++) if (l[e] > v0) { v0 = l[e]; e0 = e; }
        int e1 = -1; float v1 = -3.4e38f;
#pragma unroll
        for (int e = 0; e < 8; e++) if (e != e0 && l[e] > v1) { v1 = l[e]; e1 = e; }
        float ex = __expf(v1 - v0);
        float dn = 1.f + ex;
        wts[2*t]   = 1.f / dn;
        wts[2*t+1] = ex / dn;
        eid[2*t]   = e0;
        eid[2*t+1] = e1;
    }
}

// -------- router phase B: hierarchical perm build --------
__global__ void count_seg_kernel(const int* __restrict__ eid, int* __restrict__ segcnt) {
    int e = blockIdx.x >> 4;
    int seg = blockIdx.x & 15;
    int lane = threadIdx.x;       // 64
    int base = seg * SEGLEN;
    int cnt = 0;
    for (int i0 = 0; i0 < SEGLEN; i0 += 64) {
        bool mt = (eid[base + i0 + lane] == e);
        cnt += __popcll(__ballot(mt));
    }
    if (lane == 0) segcnt[blockIdx.x] = cnt;
}

__global__ void fill_perm_kernel(const int* __restrict__ eid, const int* __restrict__ segcnt,
                                 int* __restrict__ perm, int* __restrict__ counts) {
    int e = blockIdx.x >> 4;
    int seg = blockIdx.x & 15;
    int lane = threadIdx.x;       // 64
    int base = 0;
#pragma unroll
    for (int s2 = 0; s2 < NSEG; s2++)
        if (s2 < seg) base += segcnt[(e << 4) + s2];
    int* permE = perm + e * NTOK;
    int g0 = seg * SEGLEN;
    for (int i0 = 0; i0 < SEGLEN; i0 += 64) {
        int s = g0 + i0 + lane;
        bool mt = (eid[s] == e);
        unsigned long long mask = __ballot(mt);
        int pre = __popcll(mask & ((1ULL << lane) - 1ULL));
        if (mt) permE[base + pre] = s;
        base += __popcll(mask);
    }
    if (lane == 0 && seg == NSEG - 1) counts[e] = base;
}

// ---------------- gathered GEMM: 256x256 tile, 4-slot K-half ring, depth-3 counted vmcnt ----------
// C[M x NTOT] = gather(A)[M x KTOT] * Bt[e]^T, Bt stored [NTOT x KTOT] (B^T).
// Pipeline unit = K-half (32 of K): A 256x32 + B 256x32 = 32 KiB slot; 4-slot ring (128 KiB).
// Per half-step: vmcnt(8) [3 halves in flight -> 3-iter issue window] -> 1 raw barrier ->
// stage(h+3) interleaved with 12 ds_read_b128 + 32 MFMA (setprio). T3+T4 per guide §5.5.
// LDS placement (per operand region, rows r of 32k): 16B chunk j of row r lives at
// byte (r>>1)*128 + (((r&1)*4+j)^((r>>1)&7))*16  -> every 16-lane frag read covers all
// 8 slots of a 128B line exactly twice = 2-way = free. Global source pre-swizzled inverse.
template<int KTOT, int NTOT, bool G1>
__global__ __launch_bounds__(512, 2)
void moe_gemm(const unsigned short* __restrict__ A,
              const unsigned short* __restrict__ Bt,
              unsigned short* __restrict__ Hout,
              float* __restrict__ Out,
              const int* __restrict__ counts,
              const int* __restrict__ perm,
              const float* __restrict__ wts) {
    // bid%8 == XCD id; XCD k owns expert k. 4x4 supertiles within an expert.
    constexpr int GX = NTOT / 256;    // n-tiles: 16 (G1) or 4 (!G1)
    constexpr int SN = GX / 4;        // n-supergroups: 4 or 1
    int bid = blockIdx.y * GX + blockIdx.x;
    int e = bid & 7;
    int i = bid >> 3;
    int st = i >> 4, pos = i & 15;
    int mg = st / SN, ng = st % SN;
    int mtile = mg * 4 + (pos >> 2);
    int n0 = (ng * 4 + (pos & 3)) * 256;

    int cnt = counts[e];
    if (mtile * 256 >= cnt) return;

    __shared__ unsigned short lds[4 * 16384];   // 4 ring slots x 32 KiB = 128 KiB

    int tid = threadIdx.x;            // 512
    int lane = tid & 63;
    int wv = tid >> 6;                // 0..7
    const int* permE = perm + e * NTOK + mtile * 256;

    // ---- staging geometry (inverse of the read swizzle) ----
    // thread covers LDS 16B slots idx = i*512 + tid (i=0,1) per operand region.
    // idx -> pair p=idx>>3, slot s=idx&7; s^(p&7) = (r&1)*4 + j.
    int sp = (tid & 7) ^ ((tid >> 3) & 7);
    int r0s = 2 * (tid >> 3) + (sp >> 2);       // row for i=0; i=1 -> +128 (same j)
    int jj = sp & 3;                             // 16B chunk within the 64B k-half row
    const unsigned short* aP[2];
    const unsigned short* bP[2];
#pragma unroll
    for (int it = 0; it < 2; it++) {
        int r = r0s + it * 128;
        int s = (mtile * 256 + r < cnt) ? permE[r] : permE[0];   // clamp to a valid row
        size_t arow = G1 ? (size_t)(s >> 1) : (size_t)s;
        aP[it] = A + arow * KTOT + jj * 8;
        bP[it] = Bt + ((size_t)e * NTOT + n0 + r) * KTOT + jj * 8;
    }
    int dst0 = wv * 512;              // wave-uniform LDS elem base, i=0
    int dst1 = 4096 + wv * 512;       // i=1

    auto stage = [&](int slot, int h) {
        unsigned short* base = lds + slot * 16384;
        int off = h * 32;             // k-half h covers k in [h*32, h*32+32)
        gload_lds16(aP[0] + off, base + dst0);
        gload_lds16(aP[1] + off, base + dst1);
        gload_lds16(bP[0] + off, base + 8192 + dst0);
        gload_lds16(bP[1] + off, base + 8192 + dst1);
    };

    floatx4 acc[8][4];
    floatx4 zero = {0.f, 0.f, 0.f, 0.f};
#pragma unroll
    for (int a = 0; a < 8; a++)
#pragma unroll
        for (int b = 0; b < 4; b++) acc[a][b] = zero;

    int m = lane & 15, quad = lane >> 4;
    int wr = wv >> 2, wc = wv & 3;
    // fragment-read lane offsets (elems); mi/ni step = 16 rows = 8 pairs = 512 elems (imm-foldable)
    int sA = (((m & 1) * 4 + quad)) ^ ((m >> 1) & 7);
    int aoff = (wr * 64 + (m >> 1)) * 64 + sA * 8;
    int boff = 8192 + (wc * 32 + (m >> 1)) * 64 + sA * 8;

    auto compute_half = [&](int h) {
        const unsigned short* base = lds + ((h & 3) << 14);
        bf16x8 af[8], bfr[4];
#pragma unroll
        for (int mi = 0; mi < 8; mi++)
            af[mi] = *(const bf16x8*)(base + aoff + mi * 512);
#pragma unroll
        for (int ni = 0; ni < 4; ni++)
            bfr[ni] = *(const bf16x8*)(base + boff + ni * 512);
        asm volatile("s_waitcnt lgkmcnt(0)" ::: "memory");
        __builtin_amdgcn_sched_barrier(0);
        __builtin_amdgcn_s_setprio(1);
#pragma unroll
        for (int mi = 0; mi < 8; mi++)
#pragma unroll
            for (int ni = 0; ni < 4; ni++)
                acc[mi][ni] = __builtin_amdgcn_mfma_f32_16x16x32_bf16(af[mi], bfr[ni], acc[mi][ni], 0, 0, 0);
        __builtin_amdgcn_s_setprio(0);
    };

    constexpr int H = (KTOT / 64) * 2;   // number of K-halves: 32 (G1) / 128 (!G1)

    // prologue: 3 halves in flight (12 loads/thread)
    stage(0, 0); stage(1, 1); stage(2, 2);

    int h = 0;
#pragma unroll 4
    for (; h < H - 4; ++h) {             // H-4 = 28 / 124, multiple of 4
        WAITVM(8);                       // half h landed; h+1,h+2 stay in flight
        __builtin_amdgcn_sched_barrier(0);
        __builtin_amdgcn_s_barrier();
        __builtin_amdgcn_sched_barrier(0);
        stage((h + 3) & 3, h + 3);       // slot (h-1)&3: all reads done (barrier above)
        compute_half(h);
    }
    // peeled tail: h = H-4 (last stage), H-3, H-2, H-1
    WAITVM(8);
    __builtin_amdgcn_sched_barrier(0);
    __builtin_amdgcn_s_barrier();
    __builtin_amdgcn_sched_barrier(0);
    stage((h + 3) & 3, h + 3);
    compute_half(h); ++h;

    WAITVM(8);
    __builtin_amdgcn_sched_barrier(0);
    __builtin_amdgcn_s_barrier();
    __builtin_amdgcn_sched_barrier(0);
    compute_half(h); ++h;

    WAITVM(4);
    __builtin_amdgcn_sched_barrier(0);
    __builtin_amdgcn_s_barrier();
    __builtin_amdgcn_sched_barrier(0);
    compute_half(h); ++h;

    WAITVM(0);
    __builtin_amdgcn_sched_barrier(0);
    __builtin_amdgcn_s_barrier();
    __builtin_amdgcn_sched_barrier(0);
    compute_half(h);

    // epilogue: C/D layout col = lane&15 (+ni*16), row = quad*4 + reg (+mi*16)
    int colb = wc * 64 + m;
    int rb = wr * 128 + quad * 4;
#pragma unroll
    for (int mi = 0; mi < 8; mi++) {
#pragma unroll
        for (int reg = 0; reg < 4; reg++) {
            int rl = rb + mi * 16 + reg;
            if (mtile * 256 + rl >= cnt) continue;
            int s = permE[rl];             // 1 KiB segment, L2-hot
            if (G1) {
                unsigned short* hr = Hout + (size_t)s * NTOT + n0 + colb;
#pragma unroll
                for (int ni = 0; ni < 4; ni++) {
                    float v = acc[mi][ni][reg];
                    hr[ni * 16] = f2bf(v > 0.f ? v : 0.f);
                }
            } else {
                float w = wts[s];
                float* orow = Out + (size_t)(s >> 1) * NTOT + n0 + colb;
#pragma unroll
                for (int ni = 0; ni < 4; ni++)
                    atomicAdd(&orow[ni * 16], w * acc[mi][ni][reg]);
            }
        }
    }
}

extern "C" void kernel_launch(void* const* d_in, const int* in_sizes, int n_in,
                              void* d_out, int out_size, void* d_ws, size_t ws_size,
                              hipStream_t stream) {
    (void)in_sizes; (void)n_in; (void)out_size;
    const float* x  = (const float*)d_in[0];
    const float* gw = (const float*)d_in[1];
    const float* w1 = (const float*)d_in[2];
    const float* w2 = (const float*)d_in[3];
    float* out = (float*)d_out;
    float* logits = out + (size_t)NTOK * HD;

    char* ws = (char*)d_ws;
    int*   counts = (int*)ws;                                   // 256 B
    int*   perm   = (int*)(ws + 256);                           // 8*8192*4 = 256 KiB
    float* wts    = (float*)(ws + 256 + 262144);                // 64 KiB
    int*   eid    = (int*)(ws + 256 + 262144 + 65536);          // 64 KiB
    int*   segcnt = (int*)(ws + 393472);                        // 512 B (in the pre-xb gap)
    unsigned short* xb    = (unsigned short*)(ws + 458752);                // 16 MiB
    unsigned short* wtbuf = xb + (size_t)NTOK * HD;                        // 64 MiB (w1t, then w2t)
    unsigned short* h     = wtbuf + (size_t)NE * HD * FD;                  // 128 MiB
    size_t needed = 458752 + (size_t)NTOK*HD*2 + (size_t)NE*HD*FD*2 + (size_t)NSLOT*FD*2;
    if (ws_size < needed) return;   // workspace too small — cannot run

    hipMemsetAsync(out, 0, (size_t)NTOK * HD * sizeof(float), stream);

    // w1: [E][H][F] -> w1t [E][F][H]  (rows=H, cols=F)
    transpose_cast_kernel<<<dim3(FD / 64, HD / 64, NE), 256, 0, stream>>>(w1, wtbuf, HD, FD);
    router_kernel<<<NTOK / 4, 256, 0, stream>>>(x, gw, logits, eid, wts, xb);
    count_seg_kernel<<<NE * NSEG, 64, 0, stream>>>(eid, segcnt);
    fill_perm_kernel<<<NE * NSEG, 64, 0, stream>>>(eid, segcnt, perm, counts);
    // h[s] = relu(xb[token] @ w1[e]) : K=1024, N=4096
    moe_gemm<HD, FD, true><<<dim3(FD / 256, NE * 32), 512, 0, stream>>>(
        xb, wtbuf, h, nullptr, counts, perm, wts);
    // w2: [E][F][H] -> w2t [E][H][F] (reuse wtbuf; stream order serializes after gemm1)
    transpose_cast_kernel<<<dim3(HD / 64, FD / 64, NE), 256, 0, stream>>>(w2, wtbuf, FD, HD);
    // out[t] += w[s] * (h[s] @ w2[e]) : K=4096, N=1024
    moe_gemm<FD, HD, false><<<dim3(HD / 256, NE * 32), 512, 0, stream>>>(
        h, wtbuf, nullptr, out, counts, perm, wts);
}

// Round 4
// 730.720 us; speedup vs baseline: 1.1981x; 1.0197x over previous
//
#include <hip/hip_runtime.h>
#include <hip/hip_bf16.h>
#include <stdint.h>

#define NE 8
#define NTOK 8192        // B*T
#define HD 1024
#define FD 4096
#define NSLOT (NTOK * 2)
#define NSEG 16
#define SEGLEN (NSLOT / NSEG)

typedef __attribute__((ext_vector_type(4))) float floatx4;
typedef __attribute__((ext_vector_type(8))) __bf16 bf16x8;
typedef __attribute__((ext_vector_type(8))) unsigned short ushortx8;

__device__ __forceinline__ unsigned short f2bf(float f) {
    union { float f; unsigned u; } v; v.f = f;
    unsigned r = v.u + 0x7FFFu + ((v.u >> 16) & 1u);   // RNE
    return (unsigned short)(r >> 16);
}

__device__ __forceinline__ void gload_lds16(const unsigned short* g, unsigned short* l) {
    __builtin_amdgcn_global_load_lds(
        (const __attribute__((address_space(1))) void*)g,
        (__attribute__((address_space(3))) void*)l,
        16, 0, 0);
}

#define WAITVM(n) asm volatile("s_waitcnt vmcnt(" #n ")" ::: "memory")
#define SCHED0()  __builtin_amdgcn_sched_barrier(0)

// ------------- transpose + cast: w[e][r][c] (fp32) -> wt[e][c][r] (bf16) -------------
__global__ void transpose_cast_kernel(const float* __restrict__ w, unsigned short* __restrict__ wt,
                                      int rows, int cols) {
    __shared__ unsigned short tile[64][66];
    int e = blockIdx.z;
    int r0 = blockIdx.y * 64;
    int c0 = blockIdx.x * 64;
    const float* ws = w + (size_t)e * rows * cols;
    unsigned short* wd = wt + (size_t)e * rows * cols;
    int tid = threadIdx.x;   // 256
#pragma unroll
    for (int j = 0; j < 4; j++) {
        int idx = j * 256 + tid;
        int r = idx >> 4;
        int c4 = (idx & 15) * 4;
        float4 v = *(const float4*)(ws + (size_t)(r0 + r) * cols + c0 + c4);
        ushort2 lo, hi;
        lo.x = f2bf(v.x); lo.y = f2bf(v.y);
        hi.x = f2bf(v.z); hi.y = f2bf(v.w);
        *(ushort2*)&tile[r][c4]     = lo;
        *(ushort2*)&tile[r][c4 + 2] = hi;
    }
    __syncthreads();
#pragma unroll
    for (int j = 0; j < 2; j++) {
        int idx = j * 256 + tid;
        int c = idx >> 3;
        int r8 = (idx & 7) * 8;
        ushortx8 o;
#pragma unroll
        for (int k = 0; k < 8; k++) o[k] = tile[r8 + k][c];
        *(ushortx8*)(wd + (size_t)(c0 + c) * rows + r0 + r8) = o;
    }
}

// -------- router phase A: logits, top-2 softmax, eid/wts per slot, x->bf16 cast --------
__global__ void router_kernel(const float* __restrict__ x, const float* __restrict__ gw,
                              float* __restrict__ logits, int* __restrict__ eid,
                              float* __restrict__ wts, unsigned short* __restrict__ xb) {
    int lane = threadIdx.x & 63;
    int t = blockIdx.x * 4 + (threadIdx.x >> 6);   // one wave per token
    const float* xr = x + (size_t)t * HD;
    unsigned short* xbr = xb + (size_t)t * HD;
    float a0=0,a1=0,a2=0,a3=0,a4=0,a5=0,a6=0,a7=0;
    for (int c = lane; c < HD; c += 64) {
        float xv = xr[c];
        xbr[c] = f2bf(xv);
        const float4* g = (const float4*)(gw + (size_t)c * NE);
        float4 g0 = g[0], g1 = g[1];
        a0 += xv * g0.x; a1 += xv * g0.y; a2 += xv * g0.z; a3 += xv * g0.w;
        a4 += xv * g1.x; a5 += xv * g1.y; a6 += xv * g1.z; a7 += xv * g1.w;
    }
#pragma unroll
    for (int off = 32; off > 0; off >>= 1) {
        a0 += __shfl_xor(a0, off); a1 += __shfl_xor(a1, off);
        a2 += __shfl_xor(a2, off); a3 += __shfl_xor(a3, off);
        a4 += __shfl_xor(a4, off); a5 += __shfl_xor(a5, off);
        a6 += __shfl_xor(a6, off); a7 += __shfl_xor(a7, off);
    }
    if (lane == 0) {
        float l[8] = {a0,a1,a2,a3,a4,a5,a6,a7};
        float4 s0 = make_float4(a0,a1,a2,a3);
        float4 s1 = make_float4(a4,a5,a6,a7);
        ((float4*)(logits + (size_t)t * NE))[0] = s0;
        ((float4*)(logits + (size_t)t * NE))[1] = s1;
        int e0 = 0; float v0 = l[0];
#pragma unroll
        for (int e = 1; e < 8; e++) if (l[e] > v0) { v0 = l[e]; e0 = e; }
        int e1 = -1; float v1 = -3.4e38f;
#pragma unroll
        for (int e = 0; e < 8; e++) if (e != e0 && l[e] > v1) { v1 = l[e]; e1 = e; }
        float ex = __expf(v1 - v0);
        float dn = 1.f + ex;
        wts[2*t]   = 1.f / dn;
        wts[2*t+1] = ex / dn;
        eid[2*t]   = e0;
        eid[2*t+1] = e1;
    }
}

// -------- router phase B: hierarchical perm build --------
__global__ void count_seg_kernel(const int* __restrict__ eid, int* __restrict__ segcnt) {
    int e = blockIdx.x >> 4;
    int seg = blockIdx.x & 15;
    int lane = threadIdx.x;       // 64
    int base = seg * SEGLEN;
    int cnt = 0;
    for (int i0 = 0; i0 < SEGLEN; i0 += 64) {
        bool mt = (eid[base + i0 + lane] == e);
        cnt += __popcll(__ballot(mt));
    }
    if (lane == 0) segcnt[blockIdx.x] = cnt;
}

__global__ void fill_perm_kernel(const int* __restrict__ eid, const int* __restrict__ segcnt,
                                 int* __restrict__ perm, int* __restrict__ counts) {
    int e = blockIdx.x >> 4;
    int seg = blockIdx.x & 15;
    int lane = threadIdx.x;       // 64
    int base = 0;
#pragma unroll
    for (int s2 = 0; s2 < NSEG; s2++)
        if (s2 < seg) base += segcnt[(e << 4) + s2];
    int* permE = perm + e * NTOK;
    int g0 = seg * SEGLEN;
    for (int i0 = 0; i0 < SEGLEN; i0 += 64) {
        int s = g0 + i0 + lane;
        bool mt = (eid[s] == e);
        unsigned long long mask = __ballot(mt);
        int pre = __popcll(mask & ((1ULL << lane) - 1ULL));
        if (mt) permE[base + pre] = s;
        base += __popcll(mask);
    }
    if (lane == 0 && seg == NSEG - 1) counts[e] = base;
}

// ---------------- gathered GEMM: 256x256 tile, 16 waves, 4-slot K=32 ring ----------------
// C[M x NTOT] = gather(A)[M x KTOT] * Bt[e]^T, Bt stored [NTOT x KTOT] (B^T).
// 16 waves in 4x4 (M x N): per-wave 64x64 output = acc[4][4]; ~116 regs/wave -> 4 waves/SIMD.
// Ring slot = A 256x32 + B 256x32 = 32 KiB; 4 slots = 128 KiB LDS.
// Phase h: WAITVM(4) [half h landed, depth-2 window] -> barrier -> stage(h+3) [2 gloads]
//          -> 8 ds_read_b128 -> 16 MFMA (setprio). One barrier per phase.
// LDS bank layout: row stride 64 B, 16B chunk phys = q ^ ((r>>1)&3). Per 16-lane read
// group: buckets (m&1, phys) = 8 x 2 lanes -> 2-way = free. Staging source pre-applies
// the same involution (global addr swizzled, LDS linear).
template<int KTOT, int NTOT, bool G1>
__global__ __launch_bounds__(1024, 4)
void moe_gemm(const unsigned short* __restrict__ A,
              const unsigned short* __restrict__ Bt,
              unsigned short* __restrict__ Hout,
              float* __restrict__ Out,
              const int* __restrict__ counts,
              const int* __restrict__ perm,
              const float* __restrict__ wts) {
    // bid%8 == XCD id; XCD k owns expert k. 4x4 supertiles within an expert.
    constexpr int GX = NTOT / 256;    // n-tiles: 16 (G1) or 4 (!G1)
    constexpr int SN = GX / 4;        // n-supergroups: 4 or 1
    int bid = blockIdx.y * GX + blockIdx.x;
    int e = bid & 7;
    int i = bid >> 3;
    int st = i >> 4, pos = i & 15;
    int mg = st / SN, ng = st % SN;
    int mtile = mg * 4 + (pos >> 2);
    int n0 = (ng * 4 + (pos & 3)) * 256;

    int cnt = counts[e];
    if (mtile * 256 >= cnt) return;

    __shared__ unsigned short lds[4 * 16384];   // 4 slots x 32 KiB

    int tid = threadIdx.x;            // 1024
    int lane = tid & 63;
    int wv = tid >> 6;                // 0..15
    const int* permE = perm + e * NTOK + mtile * 256;

    // ---- staging geometry: thread covers 16B chunk idx=tid of A-half and of B-half ----
    // chunk idx -> row r = idx>>2, phys p = idx&3; global logical chunk q = p ^ ((r>>1)&3)
    int r = tid >> 2;
    int q = (tid & 3) ^ ((r >> 1) & 3);
    int sgat = (mtile * 256 + r < cnt) ? permE[r] : permE[0];   // clamp to valid row
    const unsigned short* aP = A + (G1 ? (size_t)(sgat >> 1) : (size_t)sgat) * KTOT + q * 8;
    const unsigned short* bP = Bt + ((size_t)e * NTOT + n0 + r) * KTOT + q * 8;
    int dstA = wv * 512;              // wave-uniform elem base (chunk tid -> elem tid*8)
    int dstB = 8192 + wv * 512;

    auto stage = [&](int slot, int h) {
        unsigned short* sb = lds + slot * 16384;
        int off = h * 32;             // k advances 32 elems per half
        gload_lds16(aP + off, sb + dstA);
        gload_lds16(bP + off, sb + dstB);
    };

    floatx4 acc[4][4];
    floatx4 zero = {0.f, 0.f, 0.f, 0.f};
#pragma unroll
    for (int a = 0; a < 4; a++)
#pragma unroll
        for (int b = 0; b < 4; b++) acc[a][b] = zero;

    int m = lane & 15, quad = lane >> 4;
    int wr = wv >> 2, wc = wv & 3;
    int sA = (quad ^ ((m >> 1) & 3)) * 8;            // phys chunk elem offset
    int aoff = (wr * 64 + m) * 32 + sA;              // + mi*512
    int boff = 8192 + (wc * 64 + m) * 32 + sA;       // + ni*512

    constexpr int H = KTOT / 32;      // 32 (G1) / 128 (!G1)

    // prologue: 3 halves in flight (6 loads/thread)
    stage(0, 0); stage(1, 1); stage(2, 2);

#define PHASE_BODY(hh)                                                          \
    {                                                                           \
        const unsigned short* sb = lds + (((hh) & 3) << 14);                    \
        bf16x8 af[4], bfr[4];                                                   \
        _Pragma("unroll")                                                       \
        for (int mi = 0; mi < 4; mi++)                                          \
            af[mi] = *(const bf16x8*)(sb + aoff + mi * 512);                    \
        _Pragma("unroll")                                                       \
        for (int ni = 0; ni < 4; ni++)                                          \
            bfr[ni] = *(const bf16x8*)(sb + boff + ni * 512);                   \
        __builtin_amdgcn_s_setprio(1);                                          \
        _Pragma("unroll")                                                       \
        for (int mi = 0; mi < 4; mi++)                                          \
            _Pragma("unroll")                                                   \
            for (int ni = 0; ni < 4; ni++)                                      \
                acc[mi][ni] = __builtin_amdgcn_mfma_f32_16x16x32_bf16(          \
                    af[mi], bfr[ni], acc[mi][ni], 0, 0, 0);                     \
        __builtin_amdgcn_s_setprio(0);                                          \
    }

    int h = 0;
#pragma unroll 2
    for (; h < H - 3; ++h) {          // stages halves 3..H-1
        WAITVM(4);                    // half h landed (mine); h+1,h+2 in flight
        SCHED0();
        __builtin_amdgcn_s_barrier(); // everyone's half h landed; slot (h-1) free
        SCHED0();
        stage((h + 3) & 3, h + 3);
        PHASE_BODY(h);
    }
    // h = H-3: all staged (<= H-1 issued), allow 4 = halves H-2,H-1
    WAITVM(4);
    SCHED0();
    __builtin_amdgcn_s_barrier();
    SCHED0();
    PHASE_BODY(h); ++h;
    // h = H-2: allow 2 = half H-1
    WAITVM(2);
    SCHED0();
    __builtin_amdgcn_s_barrier();
    SCHED0();
    PHASE_BODY(h); ++h;
    // h = H-1
    WAITVM(0);
    SCHED0();
    __builtin_amdgcn_s_barrier();
    SCHED0();
    PHASE_BODY(h);
#undef PHASE_BODY

    // epilogue: C/D layout col = lane&15 (+ni*16), row = quad*4 + reg (+mi*16)
    int colb = wc * 64 + m;
    int rb = wr * 64 + quad * 4;
#pragma unroll
    for (int mi = 0; mi < 4; mi++) {
#pragma unroll
        for (int reg = 0; reg < 4; reg++) {
            int rl = rb + mi * 16 + reg;
            if (mtile * 256 + rl >= cnt) continue;
            int s = permE[rl];             // 1 KiB segment, L2-hot
            if (G1) {
                unsigned short* hr = Hout + (size_t)s * NTOT + n0 + colb;
#pragma unroll
                for (int ni = 0; ni < 4; ni++) {
                    float v = acc[mi][ni][reg];
                    hr[ni * 16] = f2bf(v > 0.f ? v : 0.f);
                }
            } else {
                float w = wts[s];
                float* orow = Out + (size_t)(s >> 1) * NTOT + n0 + colb;
#pragma unroll
                for (int ni = 0; ni < 4; ni++)
                    atomicAdd(&orow[ni * 16], w * acc[mi][ni][reg]);
            }
        }
    }
}

extern "C" void kernel_launch(void* const* d_in, const int* in_sizes, int n_in,
                              void* d_out, int out_size, void* d_ws, size_t ws_size,
                              hipStream_t stream) {
    (void)in_sizes; (void)n_in; (void)out_size;
    const float* x  = (const float*)d_in[0];
    const float* gw = (const float*)d_in[1];
    const float* w1 = (const float*)d_in[2];
    const float* w2 = (const float*)d_in[3];
    float* out = (float*)d_out;
    float* logits = out + (size_t)NTOK * HD;

    char* ws = (char*)d_ws;
    int*   counts = (int*)ws;                                   // 256 B
    int*   perm   = (int*)(ws + 256);                           // 8*8192*4 = 256 KiB
    float* wts    = (float*)(ws + 256 + 262144);                // 64 KiB
    int*   eid    = (int*)(ws + 256 + 262144 + 65536);          // 64 KiB
    int*   segcnt = (int*)(ws + 393472);                        // 512 B (in the pre-xb gap)
    unsigned short* xb    = (unsigned short*)(ws + 458752);                // 16 MiB
    unsigned short* wtbuf = xb + (size_t)NTOK * HD;                        // 64 MiB (w1t, then w2t)
    unsigned short* h     = wtbuf + (size_t)NE * HD * FD;                  // 128 MiB
    size_t needed = 458752 + (size_t)NTOK*HD*2 + (size_t)NE*HD*FD*2 + (size_t)NSLOT*FD*2;
    if (ws_size < needed) return;   // workspace too small — cannot run

    hipMemsetAsync(out, 0, (size_t)NTOK * HD * sizeof(float), stream);

    // w1: [E][H][F] -> w1t [E][F][H]  (rows=H, cols=F)
    transpose_cast_kernel<<<dim3(FD / 64, HD / 64, NE), 256, 0, stream>>>(w1, wtbuf, HD, FD);
    router_kernel<<<NTOK / 4, 256, 0, stream>>>(x, gw, logits, eid, wts, xb);
    count_seg_kernel<<<NE * NSEG, 64, 0, stream>>>(eid, segcnt);
    fill_perm_kernel<<<NE * NSEG, 64, 0, stream>>>(eid, segcnt, perm, counts);
    // h[s] = relu(xb[token] @ w1[e]) : K=1024, N=4096
    moe_gemm<HD, FD, true><<<dim3(FD / 256, NE * 32), 1024, 0, stream>>>(
        xb, wtbuf, h, nullptr, counts, perm, wts);
    // w2: [E][F][H] -> w2t [E][H][F] (reuse wtbuf; stream order serializes after gemm1)
    transpose_cast_kernel<<<dim3(HD / 64, FD / 64, NE), 256, 0, stream>>>(w2, wtbuf, FD, HD);
    // out[t] += w[s] * (h[s] @ w2[e]) : K=4096, N=1024
    moe_gemm<FD, HD, false><<<dim3(HD / 256, NE * 32), 1024, 0, stream>>>(
        h, wtbuf, nullptr, out, counts, perm, wts);
}